// Round 1
// baseline (4991.249 us; speedup 1.0000x reference)
//
#include <hip/hip_runtime.h>

#define EMB 300
#define EMB4 75
#define EPS 1e-5f

__device__ __forceinline__ float4 f4add(float4 a, float4 b) {
    return make_float4(a.x + b.x, a.y + b.y, a.z + b.z, a.w + b.w);
}

// ---------------------------------------------------------------------------
// Precompute per-layer edge-embedding combos: comb[l][t0*3+t1][c] = e1[l][t0][c] + e2[l][t1][c]
// ---------------------------------------------------------------------------
__global__ void k_comb(const float* __restrict__ e1, const float* __restrict__ e2,
                       float* __restrict__ comb, int L) {
    int total = L * 18 * EMB4;
    for (int i = blockIdx.x * blockDim.x + threadIdx.x; i < total;
         i += gridDim.x * blockDim.x) {
        int l = i / (18 * EMB4);
        int r = i - l * (18 * EMB4);
        int t = r / EMB4;
        int c = r - t * EMB4;
        int t0 = t / 3, t1 = t - t0 * 3;
        float4 va = ((const float4*)(e1 + (size_t)(l * 6 + t0) * EMB))[c];
        float4 vb = ((const float4*)(e2 + (size_t)(l * 3 + t1) * EMB))[c];
        ((float4*)comb)[i] = f4add(va, vb);
    }
}

// ---------------------------------------------------------------------------
// h = x_emb1[x[:,0]] + x_emb2[x[:,1]]
// ---------------------------------------------------------------------------
__global__ void k_hinit(const int* __restrict__ x, const float* __restrict__ emb1,
                        const float* __restrict__ emb2, float* __restrict__ h, int N) {
    int total = N * EMB4;
    for (int i = blockIdx.x * blockDim.x + threadIdx.x; i < total;
         i += gridDim.x * blockDim.x) {
        int node = i / EMB4;
        int c = i - node * EMB4;
        int x0 = x[node * 2], x1 = x[node * 2 + 1];
        float4 va = ((const float4*)emb1)[x0 * EMB4 + c];
        float4 vb = ((const float4*)emb2)[x1 * EMB4 + c];
        ((float4*)h)[i] = f4add(va, vb);
    }
}

// ---------------------------------------------------------------------------
// agg[i] = h[i] + comb_self[c]  (self-loop fused; attr (4,0) -> combo 12)
// block 0 also zeroes the BN stats accumulators
// ---------------------------------------------------------------------------
__global__ void k_init_agg(const float* __restrict__ h, const float* __restrict__ combl,
                           float* __restrict__ agg, float* __restrict__ stats, int N) {
    if (blockIdx.x == 0) {
        for (int j = threadIdx.x; j < 2 * EMB; j += blockDim.x) stats[j] = 0.f;
    }
    const float4* self4 = (const float4*)(combl + 12 * EMB);
    int total = N * EMB4;
    for (int i = blockIdx.x * blockDim.x + threadIdx.x; i < total;
         i += gridDim.x * blockDim.x) {
        int c = i % EMB4;
        ((float4*)agg)[i] = f4add(((const float4*)h)[i], self4[c]);
    }
}

// ---------------------------------------------------------------------------
// Edge scatter: agg[col] += h[row] + comb[type]; one wave per edge.
// ---------------------------------------------------------------------------
__global__ __launch_bounds__(256) void k_scatter(
    const int* __restrict__ ei, const int* __restrict__ ea,
    const float* __restrict__ h, const float* __restrict__ combl,
    float* __restrict__ agg, int E) {
    __shared__ float sc[18 * EMB];
    for (int i = threadIdx.x; i < 18 * EMB; i += blockDim.x) sc[i] = combl[i];
    __syncthreads();
    int lane = threadIdx.x & 63;
    int wid = blockIdx.x * (blockDim.x >> 6) + (threadIdx.x >> 6);
    int nw = gridDim.x * (blockDim.x >> 6);
    for (int e = wid; e < E; e += nw) {
        int row = ei[e];
        int col = ei[E + e];
        int t = ea[2 * e] * 3 + ea[2 * e + 1];
        const float* hr = h + (size_t)row * EMB;
        const float* cr = sc + t * EMB;
        float* ar = agg + (size_t)col * EMB;
        #pragma unroll
        for (int c0 = 0; c0 < EMB; c0 += 64) {
            int c = c0 + lane;
            if (c < EMB) atomicAdd(ar + c, hr[c] + cr[c]);
        }
    }
}

// ---------------------------------------------------------------------------
// Tiled fp32 GEMM: C[M,N] = op(A[M,K] @ B[K,N] + bias), op = ReLU optional.
// BM x BN block tile, BK=16, 256 threads, 8x8 micro-tile.
// Constraint: BM == 16384 / BN  (BN=128->BM=128, BN=64->BM=256)
// ---------------------------------------------------------------------------
template <int BM, int BN, bool RELU>
__global__ __launch_bounds__(256) void k_gemm(
    const float* __restrict__ A, const float* __restrict__ B,
    const float* __restrict__ bias, float* __restrict__ C,
    int M, int N, int K) {
    constexpr int BK = 16;
    constexpr int TX = BN / 8;          // threads along N
    __shared__ float As[BK][BM];
    __shared__ float Bs[BK][BN];

    int tid = threadIdx.x;
    int tx = tid % TX;
    int ty = tid / TX;
    int row0 = blockIdx.y * BM;
    int col0 = blockIdx.x * BN;

    float acc[8][8] = {};

    for (int k0 = 0; k0 < K; k0 += BK) {
        // --- load A tile (BM x BK), stored transposed As[k][m] ---
        #pragma unroll
        for (int idx = tid; idx < BM * (BK / 4); idx += 256) {
            int m = idx >> 2;
            int kq = (idx & 3) << 2;
            int gm = row0 + m, gk = k0 + kq;
            float4 v = make_float4(0.f, 0.f, 0.f, 0.f);
            if (gm < M) {
                if (gk + 3 < K) {
                    v = *(const float4*)(A + (size_t)gm * K + gk);
                } else {
                    float tmp[4] = {0.f, 0.f, 0.f, 0.f};
                    for (int j = 0; j < 4; ++j)
                        if (gk + j < K) tmp[j] = A[(size_t)gm * K + gk + j];
                    v = make_float4(tmp[0], tmp[1], tmp[2], tmp[3]);
                }
            }
            As[kq + 0][m] = v.x;
            As[kq + 1][m] = v.y;
            As[kq + 2][m] = v.z;
            As[kq + 3][m] = v.w;
        }
        // --- load B tile (BK x BN) ---
        #pragma unroll
        for (int idx = tid; idx < BK * (BN / 4); idx += 256) {
            int k = idx / (BN / 4);
            int nq = (idx % (BN / 4)) << 2;
            int gk = k0 + k, gn = col0 + nq;
            float4 v = make_float4(0.f, 0.f, 0.f, 0.f);
            if (gk < K && gn < N) {
                // N is a multiple of 4 in this problem (600, 300)
                v = *(const float4*)(B + (size_t)gk * N + gn);
            }
            *(float4*)&Bs[k][nq] = v;
        }
        __syncthreads();

        #pragma unroll
        for (int k = 0; k < BK; ++k) {
            float a[8], b[8];
            *(float4*)&a[0] = *(const float4*)&As[k][ty * 8];
            *(float4*)&a[4] = *(const float4*)&As[k][ty * 8 + 4];
            *(float4*)&b[0] = *(const float4*)&Bs[k][tx * 8];
            *(float4*)&b[4] = *(const float4*)&Bs[k][tx * 8 + 4];
            #pragma unroll
            for (int i = 0; i < 8; ++i)
                #pragma unroll
                for (int j = 0; j < 8; ++j)
                    acc[i][j] = fmaf(a[i], b[j], acc[i][j]);
        }
        __syncthreads();
    }

    // --- epilogue: bias (+ReLU), float4 stores ---
    #pragma unroll
    for (int i = 0; i < 8; ++i) {
        int gm = row0 + ty * 8 + i;
        if (gm >= M) continue;
        #pragma unroll
        for (int jq = 0; jq < 2; ++jq) {
            int gn = col0 + tx * 8 + jq * 4;
            if (gn >= N) continue;   // N multiple of 4 -> full float4 valid
            float4 v;
            v.x = acc[i][jq * 4 + 0] + bias[gn + 0];
            v.y = acc[i][jq * 4 + 1] + bias[gn + 1];
            v.z = acc[i][jq * 4 + 2] + bias[gn + 2];
            v.w = acc[i][jq * 4 + 3] + bias[gn + 3];
            if (RELU) {
                v.x = fmaxf(v.x, 0.f); v.y = fmaxf(v.y, 0.f);
                v.z = fmaxf(v.z, 0.f); v.w = fmaxf(v.w, 0.f);
            }
            *(float4*)(C + (size_t)gm * N + gn) = v;
        }
    }
}

// ---------------------------------------------------------------------------
// BN stats: per-column sum and sumsq -> stats[0..299], stats[300..599]
// ---------------------------------------------------------------------------
__global__ __launch_bounds__(320) void k_bn_stats(const float* __restrict__ h2,
                                                  float* __restrict__ stats, int N) {
    int c = threadIdx.x;
    if (c >= EMB) return;
    int rpb = (N + gridDim.x - 1) / gridDim.x;
    int r0 = blockIdx.x * rpb;
    int r1 = min(N, r0 + rpb);
    float s = 0.f, q = 0.f;
    for (int r = r0; r < r1; ++r) {
        float v = h2[(size_t)r * EMB + c];
        s += v;
        q = fmaf(v, v, q);
    }
    atomicAdd(&stats[c], s);
    atomicAdd(&stats[EMB + c], q);
}

__global__ void k_bn_finalize(float* __restrict__ stats, const float* __restrict__ gamma,
                              const float* __restrict__ beta, int N) {
    int c = threadIdx.x;
    if (c >= EMB) return;
    float inv_n = 1.f / (float)N;
    float mu = stats[c] * inv_n;
    float var = stats[EMB + c] * inv_n - mu * mu;
    float sc = gamma[c] * rsqrtf(var + EPS);
    stats[2 * EMB + c] = sc;
    stats[3 * EMB + c] = beta[c] - mu * sc;
}

__global__ void k_bn_apply(const float* __restrict__ h2, const float* __restrict__ stats,
                           float* __restrict__ h, int N, int relu) {
    const float4* x4 = (const float4*)h2;
    float4* o4 = (float4*)h;
    const float4* sc4 = (const float4*)(stats + 2 * EMB);
    const float4* sh4 = (const float4*)(stats + 3 * EMB);
    int total = N * EMB4;
    for (int i = blockIdx.x * blockDim.x + threadIdx.x; i < total;
         i += gridDim.x * blockDim.x) {
        int c = i % EMB4;
        float4 v = x4[i], s = sc4[c], t = sh4[c];
        float4 r;
        r.x = fmaf(v.x, s.x, t.x);
        r.y = fmaf(v.y, s.y, t.y);
        r.z = fmaf(v.z, s.z, t.z);
        r.w = fmaf(v.w, s.w, t.w);
        if (relu) {
            r.x = fmaxf(r.x, 0.f); r.y = fmaxf(r.y, 0.f);
            r.z = fmaxf(r.z, 0.f); r.w = fmaxf(r.w, 0.f);
        }
        o4[i] = r;
    }
}

// ---------------------------------------------------------------------------
extern "C" void kernel_launch(void* const* d_in, const int* in_sizes, int n_in,
                              void* d_out, int out_size, void* d_ws, size_t ws_size,
                              hipStream_t stream) {
    const int*   x      = (const int*)d_in[0];
    const int*   ei     = (const int*)d_in[1];
    const int*   ea     = (const int*)d_in[2];
    const float* x_emb1 = (const float*)d_in[3];
    const float* x_emb2 = (const float*)d_in[4];
    const float* e1     = (const float*)d_in[5];
    const float* e2     = (const float*)d_in[6];
    const float* W1     = (const float*)d_in[7];
    const float* b1     = (const float*)d_in[8];
    const float* W2     = (const float*)d_in[9];
    const float* b2     = (const float*)d_in[10];
    const float* gamma  = (const float*)d_in[11];
    const float* beta   = (const float*)d_in[12];
    float* out = (float*)d_out;

    int N = in_sizes[0] / 2;
    int E = in_sizes[2] / 2;
    int L = in_sizes[7] / (EMB * 2 * EMB);

    float* ws    = (float*)d_ws;
    float* comb  = ws;                    // L*18*300 floats (27000)
    float* stats = ws + 32768;            // 1200 floats: sum, sumsq, scale, shift
    float* agg   = ws + 65536;            // N*300 floats  (also reused as h2)
    float* hm    = agg + (size_t)N * EMB; // N*600 floats

    k_comb<<<64, 256, 0, stream>>>(e1, e2, comb, L);
    k_hinit<<<2048, 256, 0, stream>>>(x, x_emb1, x_emb2, out, N);

    for (int l = 0; l < L; ++l) {
        const float* combl = comb + (size_t)l * 18 * EMB;
        k_init_agg<<<2048, 256, 0, stream>>>(out, combl, agg, stats, N);
        k_scatter<<<1024, 256, 0, stream>>>(ei, ea, out, combl, agg, E);

        dim3 g1((2 * EMB + 127) / 128, (N + 127) / 128);
        k_gemm<128, 128, true><<<g1, 256, 0, stream>>>(
            agg, W1 + (size_t)l * EMB * 2 * EMB, b1 + (size_t)l * 2 * EMB,
            hm, N, 2 * EMB, EMB);

        dim3 g2((EMB + 63) / 64, (N + 255) / 256);
        k_gemm<256, 64, false><<<g2, 256, 0, stream>>>(
            hm, W2 + (size_t)l * 2 * EMB * EMB, b2 + (size_t)l * EMB,
            agg /*h2*/, N, EMB, 2 * EMB);

        k_bn_stats<<<250, 320, 0, stream>>>(agg, stats, N);
        k_bn_finalize<<<1, 320, 0, stream>>>(stats, gamma + (size_t)l * EMB,
                                             beta + (size_t)l * EMB, N);
        k_bn_apply<<<2048, 256, 0, stream>>>(agg, stats, out, N, (l < L - 1) ? 1 : 0);
    }
}

// Round 3
// 4133.405 us; speedup vs baseline: 1.2075x; 1.2075x over previous
//
#include <hip/hip_runtime.h>

#define EMB 300
#define EMB4 75
#define EPS 1e-5f

typedef _Float16 half_t;
using f16x8 = __attribute__((ext_vector_type(8))) _Float16;
using f32x4 = __attribute__((ext_vector_type(4))) float;

__device__ __forceinline__ float4 f4add(float4 a, float4 b) {
    return make_float4(a.x + b.x, a.y + b.y, a.z + b.z, a.w + b.w);
}

// ---------------------------------------------------------------------------
// h = x_emb1[x[:,0]] + x_emb2[x[:,1]]
// ---------------------------------------------------------------------------
__global__ void k_hinit(const int* __restrict__ x, const float* __restrict__ emb1,
                        const float* __restrict__ emb2, float* __restrict__ h, int N) {
    int total = N * EMB4;
    for (int i = blockIdx.x * blockDim.x + threadIdx.x; i < total;
         i += gridDim.x * blockDim.x) {
        int node = i / EMB4;
        int c = i - node * EMB4;
        int x0 = x[node * 2], x1 = x[node * 2 + 1];
        float4 va = ((const float4*)emb1)[x0 * EMB4 + c];
        float4 vb = ((const float4*)emb2)[x1 * EMB4 + c];
        ((float4*)h)[i] = f4add(va, vb);
    }
}

// ---------------------------------------------------------------------------
// agg[i] = h[i] + self_combo[c]; self-loop attr = (4,0)
// block 0 zeroes BN stats accumulators
// ---------------------------------------------------------------------------
__global__ void k_init_agg(const float* __restrict__ h, const float* __restrict__ e1l,
                           const float* __restrict__ e2l,
                           float* __restrict__ agg, float* __restrict__ stats, int N) {
    if (blockIdx.x == 0) {
        for (int j = threadIdx.x; j < 2 * EMB; j += blockDim.x) stats[j] = 0.f;
    }
    const float4* s1 = (const float4*)(e1l + 4 * EMB);  // edge_emb1[l][4]
    const float4* s2 = (const float4*)(e2l);            // edge_emb2[l][0]
    int total = N * EMB4;
    for (int i = blockIdx.x * blockDim.x + threadIdx.x; i < total;
         i += gridDim.x * blockDim.x) {
        int c = i % EMB4;
        ((float4*)agg)[i] = f4add(((const float4*)h)[i], f4add(s1[c], s2[c]));
    }
}

// ---------------------------------------------------------------------------
// Edge scatter: agg[col] += h[row] + comb[type]; one wave per edge.
// Combos built in LDS from the layer's edge embeddings.
// ---------------------------------------------------------------------------
__global__ __launch_bounds__(256) void k_scatter(
    const int* __restrict__ ei, const int* __restrict__ ea,
    const float* __restrict__ h, const float* __restrict__ e1l,
    const float* __restrict__ e2l, float* __restrict__ agg, int E) {
    __shared__ float sc[18 * EMB];
    for (int i = threadIdx.x; i < 18 * EMB; i += blockDim.x) {
        int t = i / EMB, c = i - t * EMB;
        sc[i] = e1l[(t / 3) * EMB + c] + e2l[(t % 3) * EMB + c];
    }
    __syncthreads();
    int lane = threadIdx.x & 63;
    int wid = blockIdx.x * (blockDim.x >> 6) + (threadIdx.x >> 6);
    int nw = gridDim.x * (blockDim.x >> 6);
    for (int e = wid; e < E; e += nw) {
        int row = ei[e];
        int col = ei[E + e];
        int t = ea[2 * e] * 3 + ea[2 * e + 1];
        const float* hr = h + (size_t)row * EMB;
        const float* cr = sc + t * EMB;
        float* ar = agg + (size_t)col * EMB;
        #pragma unroll
        for (int c0 = 0; c0 < EMB; c0 += 64) {
            int c = c0 + lane;
            if (c < EMB) atomicAdd(ar + c, hr[c] + cr[c]);
        }
    }
}

// ---------------------------------------------------------------------------
// Weight pre-transpose + fp16-split conversion:
// W [K][N] fp32 -> Bt_hi/Bt_lo [N][Kpad] f16 (lo pre-scaled by 4096)
// ---------------------------------------------------------------------------
__global__ void k_cvtB(const float* __restrict__ W, half_t* __restrict__ bh,
                       half_t* __restrict__ bl, int K, int N, int Kpad) {
    int cpr = Kpad >> 3;
    int total = N * cpr;
    for (int i = blockIdx.x * blockDim.x + threadIdx.x; i < total;
         i += gridDim.x * blockDim.x) {
        int n = i / cpr;
        int ch = i - n * cpr;
        f16x8 hi, lo;
        #pragma unroll
        for (int j = 0; j < 8; ++j) {
            int k = ch * 8 + j;
            float v = (k < K) ? W[(size_t)k * N + n] : 0.f;
            half_t h = (half_t)v;
            hi[j] = h;
            lo[j] = (half_t)((v - (float)h) * 4096.f);
        }
        *(f16x8*)&bh[(size_t)n * Kpad + ch * 8] = hi;
        *(f16x8*)&bl[(size_t)n * Kpad + ch * 8] = lo;
    }
}

// ---------------------------------------------------------------------------
// Split-fp16 MFMA GEMM: C = op(A @ B^T_planes + bias)
// 128x128 tile, BK=32, 256 threads = 4 waves (2x2), 64x64 per wave.
// MODE 0: A fp32 [M][K] (convert in staging), OUT packed u32(lo16|hi16), ReLU.
// MODE 1: A packed u32 [M][K],                OUT fp32, no ReLU.
// LDS swizzle: 16B-slot index ^= (row>>1)&3  (uniform bank groups, verified).
// ---------------------------------------------------------------------------
template <int MODE>
__global__ __launch_bounds__(256) void k_mfma_gemm(
    const void* __restrict__ Ain,
    const half_t* __restrict__ Bh, const half_t* __restrict__ Bl,
    const float* __restrict__ bias, void* __restrict__ Cout,
    int M, int N, int K, int Kpad)
{
    __shared__ half_t sAh[128 * 32], sAl[128 * 32], sBh[128 * 32], sBl[128 * 32];
    const int tid = threadIdx.x;
    const int lane = tid & 63, wid = tid >> 6;
    const int lr = lane & 15, ls = lane >> 4;
    const int wr = wid >> 1, wc = wid & 1;
    const int row0 = blockIdx.y * 128, col0 = blockIdx.x * 128;

    // A staging mapping: row sm = tid>>1, chunk pair {2*kh, 2*kh+1} of 8 halves
    const int sm = tid >> 1;
    const int kh = tid & 1;
    size_t arow = row0 + sm; if (arow >= (size_t)M) arow = M - 1;
    const int aswz = (sm >> 1) & 3;

    f32x4 acc1[4][4], acc2[4][4];
    #pragma unroll
    for (int i = 0; i < 4; ++i)
        #pragma unroll
        for (int j = 0; j < 4; ++j) {
            acc1[i][j] = (f32x4){0.f, 0.f, 0.f, 0.f};
            acc2[i][j] = (f32x4){0.f, 0.f, 0.f, 0.f};
        }

    const int nsteps = Kpad / 32;
    for (int s = 0; s < nsteps; ++s) {
        const int k0 = s * 32;

        // ---------- stage B: async global->LDS, pre-swizzled source ----------
        #pragma unroll
        for (int jj = 0; jj < 2; ++jj) {
            int j = wid * 2 + jj;
            int nl = j * 16 + (lane >> 2);
            int t = lane & 3;
            int ch = t ^ ((nl >> 1) & 3);
            size_t brow = col0 + nl; if (brow >= (size_t)N) brow = N - 1;
            const half_t* gh = Bh + brow * Kpad + k0 + ch * 8;
            const half_t* gl = Bl + brow * Kpad + k0 + ch * 8;
            __builtin_amdgcn_global_load_lds(
                (const __attribute__((address_space(1))) void*)gh,
                (__attribute__((address_space(3))) void*)&sBh[j * 512], 16, 0, 0);
            __builtin_amdgcn_global_load_lds(
                (const __attribute__((address_space(1))) void*)gl,
                (__attribute__((address_space(3))) void*)&sBl[j * 512], 16, 0, 0);
        }

        // ---------- stage A ----------
        if (MODE == 0) {
            const float* A = (const float*)Ain;
            const float* ap = A + arow * K;
            float va[16];
            #pragma unroll
            for (int q = 0; q < 4; ++q) {
                int gk = k0 + kh * 16 + q * 4;
                float4 v = make_float4(0.f, 0.f, 0.f, 0.f);
                if (gk < K) v = *(const float4*)(ap + gk);
                va[q * 4 + 0] = v.x; va[q * 4 + 1] = v.y;
                va[q * 4 + 2] = v.z; va[q * 4 + 3] = v.w;
            }
            #pragma unroll
            for (int c = 0; c < 2; ++c) {
                f16x8 hi, lo;
                #pragma unroll
                for (int j = 0; j < 8; ++j) {
                    float xv = va[c * 8 + j];
                    half_t h = (half_t)xv;
                    hi[j] = h;
                    lo[j] = (half_t)((xv - (float)h) * 4096.f);
                }
                int slot = (kh * 2 + c) ^ aswz;
                *(f16x8*)&sAh[sm * 32 + slot * 8] = hi;
                *(f16x8*)&sAl[sm * 32 + slot * 8] = lo;
            }
        } else {
            const unsigned* A = (const unsigned*)Ain;
            #pragma unroll
            for (int c = 0; c < 2; ++c) {
                int u = kh * 2 + c;
                int gk = k0 + u * 8;
                f16x8 hi, lo;
                if (gk < K) {
                    const unsigned* p = A + arow * K + gk;
                    uint4 w0 = *(const uint4*)p;
                    uint4 w1 = *(const uint4*)(p + 4);
                    unsigned wv[8] = {w0.x, w0.y, w0.z, w0.w, w1.x, w1.y, w1.z, w1.w};
                    #pragma unroll
                    for (int j = 0; j < 8; ++j) {
                        union { unsigned short u16; half_t h; } a, b;
                        a.u16 = (unsigned short)(wv[j] & 0xffffu);
                        b.u16 = (unsigned short)(wv[j] >> 16);
                        hi[j] = a.h; lo[j] = b.h;
                    }
                } else {
                    #pragma unroll
                    for (int j = 0; j < 8; ++j) { hi[j] = (half_t)0.f; lo[j] = (half_t)0.f; }
                }
                int slot = u ^ aswz;
                *(f16x8*)&sAh[sm * 32 + slot * 8] = hi;
                *(f16x8*)&sAl[sm * 32 + slot * 8] = lo;
            }
        }
        __syncthreads();

        // ---------- compute: 48 MFMAs per wave ----------
        const int frswz = (lr >> 1) & 3;
        f16x8 bhf[4], blf[4];
        #pragma unroll
        for (int fn = 0; fn < 4; ++fn) {
            int noff = (wc * 64 + fn * 16 + lr) * 32 + (ls ^ frswz) * 8;
            bhf[fn] = *(const f16x8*)&sBh[noff];
            blf[fn] = *(const f16x8*)&sBl[noff];
        }
        #pragma unroll
        for (int fm = 0; fm < 4; ++fm) {
            int moff = (wr * 64 + fm * 16 + lr) * 32 + (ls ^ frswz) * 8;
            f16x8 ah = *(const f16x8*)&sAh[moff];
            f16x8 al = *(const f16x8*)&sAl[moff];
            #pragma unroll
            for (int fn = 0; fn < 4; ++fn) {
                acc1[fm][fn] = __builtin_amdgcn_mfma_f32_16x16x32_f16(ah, bhf[fn], acc1[fm][fn], 0, 0, 0);
                acc2[fm][fn] = __builtin_amdgcn_mfma_f32_16x16x32_f16(ah, blf[fn], acc2[fm][fn], 0, 0, 0);
                acc2[fm][fn] = __builtin_amdgcn_mfma_f32_16x16x32_f16(al, bhf[fn], acc2[fm][fn], 0, 0, 0);
            }
        }
        __syncthreads();
    }

    // ---------- epilogue ----------
    const float inv = 1.f / 4096.f;
    #pragma unroll
    for (int fn = 0; fn < 4; ++fn) {
        int gcol = col0 + wc * 64 + fn * 16 + lr;
        if (gcol >= N) continue;
        float bv = bias[gcol];
        #pragma unroll
        for (int fm = 0; fm < 4; ++fm) {
            int growb = row0 + wr * 64 + fm * 16 + ls * 4;
            #pragma unroll
            for (int r = 0; r < 4; ++r) {
                int grow = growb + r;
                if (grow >= M) continue;
                float val = acc1[fm][fn][r] + acc2[fm][fn][r] * inv + bv;
                if (MODE == 0) {
                    val = fmaxf(val, 0.f);
                    half_t h = (half_t)val;
                    half_t l2 = (half_t)((val - (float)h) * 4096.f);
                    union { half_t h; unsigned short u; } uh, ul;
                    uh.h = h; ul.h = l2;
                    ((unsigned*)Cout)[(size_t)grow * N + gcol] =
                        ((unsigned)ul.u << 16) | (unsigned)uh.u;
                } else {
                    ((float*)Cout)[(size_t)grow * N + gcol] = val;
                }
            }
        }
    }
}

// ---------------------------------------------------------------------------
// BN stats: per-column sum and sumsq
// ---------------------------------------------------------------------------
__global__ __launch_bounds__(320) void k_bn_stats(const float* __restrict__ h2,
                                                  float* __restrict__ stats, int N) {
    int c = threadIdx.x;
    if (c >= EMB) return;
    int rpb = (N + gridDim.x - 1) / gridDim.x;
    int r0 = blockIdx.x * rpb;
    int r1 = min(N, r0 + rpb);
    float s = 0.f, q = 0.f;
    for (int r = r0; r < r1; ++r) {
        float v = h2[(size_t)r * EMB + c];
        s += v;
        q = fmaf(v, v, q);
    }
    atomicAdd(&stats[c], s);
    atomicAdd(&stats[EMB + c], q);
}

__global__ void k_bn_finalize(float* __restrict__ stats, const float* __restrict__ gamma,
                              const float* __restrict__ beta, int N) {
    int c = threadIdx.x;
    if (c >= EMB) return;
    float inv_n = 1.f / (float)N;
    float mu = stats[c] * inv_n;
    float var = stats[EMB + c] * inv_n - mu * mu;
    float sc = gamma[c] * rsqrtf(var + EPS);
    stats[2 * EMB + c] = sc;
    stats[3 * EMB + c] = beta[c] - mu * sc;
}

__global__ void k_bn_apply(const float* __restrict__ h2, const float* __restrict__ stats,
                           float* __restrict__ h, int N, int relu) {
    const float4* x4 = (const float4*)h2;
    float4* o4 = (float4*)h;
    const float4* sc4 = (const float4*)(stats + 2 * EMB);
    const float4* sh4 = (const float4*)(stats + 3 * EMB);
    int total = N * EMB4;
    for (int i = blockIdx.x * blockDim.x + threadIdx.x; i < total;
         i += gridDim.x * blockDim.x) {
        int c = i % EMB4;
        float4 v = x4[i], s = sc4[c], t = sh4[c];
        float4 r;
        r.x = fmaf(v.x, s.x, t.x);
        r.y = fmaf(v.y, s.y, t.y);
        r.z = fmaf(v.z, s.z, t.z);
        r.w = fmaf(v.w, s.w, t.w);
        if (relu) {
            r.x = fmaxf(r.x, 0.f); r.y = fmaxf(r.y, 0.f);
            r.z = fmaxf(r.z, 0.f); r.w = fmaxf(r.w, 0.f);
        }
        o4[i] = r;
    }
}

// ---------------------------------------------------------------------------
extern "C" void kernel_launch(void* const* d_in, const int* in_sizes, int n_in,
                              void* d_out, int out_size, void* d_ws, size_t ws_size,
                              hipStream_t stream) {
    const int*   x      = (const int*)d_in[0];
    const int*   ei     = (const int*)d_in[1];
    const int*   ea     = (const int*)d_in[2];
    const float* x_emb1 = (const float*)d_in[3];
    const float* x_emb2 = (const float*)d_in[4];
    const float* e1     = (const float*)d_in[5];
    const float* e2     = (const float*)d_in[6];
    const float* W1     = (const float*)d_in[7];
    const float* b1     = (const float*)d_in[8];
    const float* W2     = (const float*)d_in[9];
    const float* b2     = (const float*)d_in[10];
    const float* gamma  = (const float*)d_in[11];
    const float* beta   = (const float*)d_in[12];
    float* out = (float*)d_out;

    int N = in_sizes[0] / 2;
    int E = in_sizes[2] / 2;
    int L = in_sizes[7] / (EMB * 2 * EMB);

    // workspace: stats @0 (1200), agg fp32 @4096 (15M), hm packed u32 (30M words)
    // total = 45,004,096 floats (< round-1's proven 45,065,536 footprint)
    float*    ws    = (float*)d_ws;
    float*    stats = ws;
    float*    agg   = ws + 4096;
    unsigned* hm    = (unsigned*)(ws + 4096 + (size_t)N * EMB);

    // weight planes live in d_out's dead window (between scatter and bn_apply)
    half_t* b1h = (half_t*)d_out;
    half_t* b1l = b1h + (size_t)600 * 320;
    half_t* b2h = (half_t*)d_out;
    half_t* b2l = b2h + (size_t)300 * 608;

    k_hinit<<<2048, 256, 0, stream>>>(x, x_emb1, x_emb2, out, N);

    int rowblks = (N + 127) / 128;
    for (int l = 0; l < L; ++l) {
        const float* e1l = e1 + (size_t)l * 6 * EMB;
        const float* e2l = e2 + (size_t)l * 3 * EMB;

        k_init_agg<<<2048, 256, 0, stream>>>(out, e1l, e2l, agg, stats, N);
        k_scatter<<<1024, 256, 0, stream>>>(ei, ea, out, e1l, e2l, agg, E);

        // h (d_out) is dead from here until bn_apply -> borrow for weight planes
        k_cvtB<<<128, 256, 0, stream>>>(W1 + (size_t)l * EMB * 2 * EMB,
                                        b1h, b1l, EMB, 2 * EMB, 320);
        dim3 g1(5, rowblks);
        k_mfma_gemm<0><<<g1, 256, 0, stream>>>(
            agg, b1h, b1l, b1 + (size_t)l * 2 * EMB, hm, N, 2 * EMB, EMB, 320);

        k_cvtB<<<128, 256, 0, stream>>>(W2 + (size_t)l * 2 * EMB * EMB,
                                        b2h, b2l, 2 * EMB, EMB, 608);
        dim3 g2(3, rowblks);
        k_mfma_gemm<1><<<g2, 256, 0, stream>>>(
            hm, b2h, b2l, b2 + (size_t)l * EMB, agg, N, EMB, 2 * EMB, 608);

        k_bn_stats<<<250, 320, 0, stream>>>(agg, stats, N);
        k_bn_finalize<<<1, 320, 0, stream>>>(stats, gamma + (size_t)l * EMB,
                                             beta + (size_t)l * EMB, N);
        k_bn_apply<<<2048, 256, 0, stream>>>(agg, stats, out, N, (l < L - 1) ? 1 : 0);
    }
}

// Round 6
// 3156.483 us; speedup vs baseline: 1.5813x; 1.3095x over previous
//
#include <hip/hip_runtime.h>

#define EMB 300
#define EMB4 75
#define EPS 1e-5f

typedef _Float16 half_t;
using f16x8 = __attribute__((ext_vector_type(8))) _Float16;
using f32x4 = __attribute__((ext_vector_type(4))) float;

__device__ __forceinline__ float4 f4add(float4 a, float4 b) {
    return make_float4(a.x + b.x, a.y + b.y, a.z + b.z, a.w + b.w);
}

// ---------------------------------------------------------------------------
// h = x_emb1[x[:,0]] + x_emb2[x[:,1]]
// ---------------------------------------------------------------------------
__global__ void k_hinit(const int* __restrict__ x, const float* __restrict__ emb1,
                        const float* __restrict__ emb2, float* __restrict__ h, int N) {
    int total = N * EMB4;
    for (int i = blockIdx.x * blockDim.x + threadIdx.x; i < total;
         i += gridDim.x * blockDim.x) {
        int node = i / EMB4;
        int c = i - node * EMB4;
        int x0 = x[node * 2], x1 = x[node * 2 + 1];
        float4 va = ((const float4*)emb1)[x0 * EMB4 + c];
        float4 vb = ((const float4*)emb2)[x1 * EMB4 + c];
        ((float4*)h)[i] = f4add(va, vb);
    }
}

// ---------------------------------------------------------------------------
// CSR build (once per call): histogram -> prefix scan -> permute
// packed[e] = src_row | (edge_type << 20)
// ---------------------------------------------------------------------------
__global__ void k_zero(int* __restrict__ p, int n) {
    for (int i = blockIdx.x * blockDim.x + threadIdx.x; i < n;
         i += gridDim.x * blockDim.x) p[i] = 0;
}

__global__ void k_hist(const int* __restrict__ ei, int* __restrict__ deg, int E) {
    for (int e = blockIdx.x * blockDim.x + threadIdx.x; e < E;
         e += gridDim.x * blockDim.x) atomicAdd(&deg[ei[E + e]], 1);
}

__global__ __launch_bounds__(1024) void k_prefix(const int* __restrict__ deg,
                                                 int* __restrict__ start,
                                                 int* __restrict__ cursor, int N) {
    __shared__ int part[1024];
    int tid = threadIdx.x;
    int per = (N + 1023) / 1024;
    int i0 = tid * per;
    int i1 = min(N, i0 + per);
    int s = 0;
    for (int i = i0; i < i1; ++i) s += deg[i];
    part[tid] = s;
    __syncthreads();
    for (int off = 1; off < 1024; off <<= 1) {
        int v = (tid >= off) ? part[tid - off] : 0;
        __syncthreads();
        part[tid] += v;
        __syncthreads();
    }
    int base = (tid == 0) ? 0 : part[tid - 1];
    for (int i = i0; i < i1; ++i) {
        start[i] = base;
        cursor[i] = base;
        base += deg[i];
    }
    if (tid == 1023) start[N] = part[1023];
}

__global__ void k_permute(const int* __restrict__ ei, const int* __restrict__ ea,
                          int* __restrict__ cursor, int* __restrict__ packed, int E) {
    for (int e = blockIdx.x * blockDim.x + threadIdx.x; e < E;
         e += gridDim.x * blockDim.x) {
        int col = ei[E + e];
        int pos = atomicAdd(&cursor[col], 1);
        int t = ea[2 * e] * 3 + ea[2 * e + 1];
        packed[pos] = ei[e] | (t << 20);
    }
}

// ---------------------------------------------------------------------------
// CSR aggregation: one wave per destination node, accumulators in registers.
// agg[i] = h[i] + self_combo + sum_{e: col=i} (h[row_e] + comb[t_e])
// Self-loop attr (4,0) -> combo index 12. Block 0 zeroes BN stats.
// ---------------------------------------------------------------------------
__global__ __launch_bounds__(256) void k_agg_csr(
    const int* __restrict__ start, const int* __restrict__ packed,
    const float* __restrict__ h, const float* __restrict__ e1l,
    const float* __restrict__ e2l, float* __restrict__ agg,
    float* __restrict__ stats, int N) {
    __shared__ float sc[18 * EMB];
    for (int i = threadIdx.x; i < 18 * EMB; i += blockDim.x) {
        int t = i / EMB, c = i - t * EMB;
        sc[i] = e1l[(t / 3) * EMB + c] + e2l[(t % 3) * EMB + c];
    }
    if (blockIdx.x == 0) {
        for (int j = threadIdx.x; j < 2 * EMB; j += blockDim.x) stats[j] = 0.f;
    }
    __syncthreads();

    int lane = threadIdx.x & 63;
    int node = blockIdx.x * 4 + (threadIdx.x >> 6);
    if (node >= N) return;

    const bool has1 = lane < (EMB4 - 64);   // lanes 0..10 own chunks 64..74
    const float4* hp = (const float4*)(h + (size_t)node * EMB);
    const float4* scp = (const float4*)(sc + 12 * EMB);
    float4 a0 = f4add(hp[lane], scp[lane]);
    float4 a1;
    if (has1) a1 = f4add(hp[lane + 64], scp[lane + 64]);

    int s0 = start[node], s1 = start[node + 1];
    for (int e = s0; e < s1; ++e) {
        int p = __builtin_amdgcn_readfirstlane(packed[e]);
        int row = p & 0xFFFFF;
        int t = p >> 20;
        const float4* hr = (const float4*)(h + (size_t)row * EMB);
        const float4* cr = (const float4*)(sc + t * EMB);
        a0 = f4add(a0, f4add(hr[lane], cr[lane]));
        if (has1) a1 = f4add(a1, f4add(hr[lane + 64], cr[lane + 64]));
    }
    float4* ap = (float4*)(agg + (size_t)node * EMB);
    ap[lane] = a0;
    if (has1) ap[lane + 64] = a1;
}

// ---------------------------------------------------------------------------
// Weight pre-transpose + fp16-split conversion:
// W [K][N] fp32 -> Bt_hi/Bt_lo [N][Kpad] f16 (lo pre-scaled by 4096)
// ---------------------------------------------------------------------------
__global__ void k_cvtB(const float* __restrict__ W, half_t* __restrict__ bh,
                       half_t* __restrict__ bl, int K, int N, int Kpad) {
    int cpr = Kpad >> 3;
    int total = N * cpr;
    for (int i = blockIdx.x * blockDim.x + threadIdx.x; i < total;
         i += gridDim.x * blockDim.x) {
        int n = i / cpr;
        int ch = i - n * cpr;
        f16x8 hi, lo;
        #pragma unroll
        for (int j = 0; j < 8; ++j) {
            int k = ch * 8 + j;
            float v = (k < K) ? W[(size_t)k * N + n] : 0.f;
            half_t h = (half_t)v;
            hi[j] = h;
            lo[j] = (half_t)((v - (float)h) * 4096.f);
        }
        *(f16x8*)&bh[(size_t)n * Kpad + ch * 8] = hi;
        *(f16x8*)&bl[(size_t)n * Kpad + ch * 8] = lo;
    }
}

// ---------------------------------------------------------------------------
// Split-fp16 MFMA GEMM: C = op(A @ B^T_planes + bias)
// 128x128 tile, BK=32, 256 threads = 4 waves (2x2), 64x64 per wave.
// MODE 0: A fp32 [M][K] (convert in staging), OUT packed u32(lo16|hi16), ReLU.
// MODE 1: A packed u32 [M][K],                OUT fp32, no ReLU.
// LDS swizzle: 16B-slot index ^= (row>>1)&3  (uniform bank groups, verified).
// ---------------------------------------------------------------------------
template <int MODE>
__global__ __launch_bounds__(256) void k_mfma_gemm(
    const void* __restrict__ Ain,
    const half_t* __restrict__ Bh, const half_t* __restrict__ Bl,
    const float* __restrict__ bias, void* __restrict__ Cout,
    int M, int N, int K, int Kpad)
{
    __shared__ half_t sAh[128 * 32], sAl[128 * 32], sBh[128 * 32], sBl[128 * 32];
    const int tid = threadIdx.x;
    const int lane = tid & 63, wid = tid >> 6;
    const int lr = lane & 15, ls = lane >> 4;
    const int wr = wid >> 1, wc = wid & 1;
    const int row0 = blockIdx.y * 128, col0 = blockIdx.x * 128;

    const int sm = tid >> 1;
    const int kh = tid & 1;
    size_t arow = row0 + sm; if (arow >= (size_t)M) arow = M - 1;
    const int aswz = (sm >> 1) & 3;

    f32x4 acc1[4][4], acc2[4][4];
    #pragma unroll
    for (int i = 0; i < 4; ++i)
        #pragma unroll
        for (int j = 0; j < 4; ++j) {
            acc1[i][j] = (f32x4){0.f, 0.f, 0.f, 0.f};
            acc2[i][j] = (f32x4){0.f, 0.f, 0.f, 0.f};
        }

    const int nsteps = Kpad / 32;
    for (int s = 0; s < nsteps; ++s) {
        const int k0 = s * 32;

        // ---------- stage B: async global->LDS, pre-swizzled source ----------
        #pragma unroll
        for (int jj = 0; jj < 2; ++jj) {
            int j = wid * 2 + jj;
            int nl = j * 16 + (lane >> 2);
            int t = lane & 3;
            int ch = t ^ ((nl >> 1) & 3);
            size_t brow = col0 + nl; if (brow >= (size_t)N) brow = N - 1;
            const half_t* gh = Bh + brow * Kpad + k0 + ch * 8;
            const half_t* gl = Bl + brow * Kpad + k0 + ch * 8;
            __builtin_amdgcn_global_load_lds(
                (const __attribute__((address_space(1))) void*)gh,
                (__attribute__((address_space(3))) void*)&sBh[j * 512], 16, 0, 0);
            __builtin_amdgcn_global_load_lds(
                (const __attribute__((address_space(1))) void*)gl,
                (__attribute__((address_space(3))) void*)&sBl[j * 512], 16, 0, 0);
        }

        // ---------- stage A ----------
        if (MODE == 0) {
            const float* A = (const float*)Ain;
            const float* ap = A + arow * K;
            float va[16];
            #pragma unroll
            for (int q = 0; q < 4; ++q) {
                int gk = k0 + kh * 16 + q * 4;
                float4 v = make_float4(0.f, 0.f, 0.f, 0.f);
                if (gk < K) v = *(const float4*)(ap + gk);
                va[q * 4 + 0] = v.x; va[q * 4 + 1] = v.y;
                va[q * 4 + 2] = v.z; va[q * 4 + 3] = v.w;
            }
            #pragma unroll
            for (int c = 0; c < 2; ++c) {
                f16x8 hi, lo;
                #pragma unroll
                for (int j = 0; j < 8; ++j) {
                    float xv = va[c * 8 + j];
                    half_t h = (half_t)xv;
                    hi[j] = h;
                    lo[j] = (half_t)((xv - (float)h) * 4096.f);
                }
                int slot = (kh * 2 + c) ^ aswz;
                *(f16x8*)&sAh[sm * 32 + slot * 8] = hi;
                *(f16x8*)&sAl[sm * 32 + slot * 8] = lo;
            }
        } else {
            const unsigned* A = (const unsigned*)Ain;
            #pragma unroll
            for (int c = 0; c < 2; ++c) {
                int u = kh * 2 + c;
                int gk = k0 + u * 8;
                f16x8 hi, lo;
                if (gk < K) {
                    const unsigned* p = A + arow * K + gk;
                    uint4 w0 = *(const uint4*)p;
                    uint4 w1 = *(const uint4*)(p + 4);
                    unsigned wv[8] = {w0.x, w0.y, w0.z, w0.w, w1.x, w1.y, w1.z, w1.w};
                    #pragma unroll
                    for (int j = 0; j < 8; ++j) {
                        union { unsigned short u16; half_t h; } a, b;
                        a.u16 = (unsigned short)(wv[j] & 0xffffu);
                        b.u16 = (unsigned short)(wv[j] >> 16);
                        hi[j] = a.h; lo[j] = b.h;
                    }
                } else {
                    #pragma unroll
                    for (int j = 0; j < 8; ++j) { hi[j] = (half_t)0.f; lo[j] = (half_t)0.f; }
                }
                int slot = u ^ aswz;
                *(f16x8*)&sAh[sm * 32 + slot * 8] = hi;
                *(f16x8*)&sAl[sm * 32 + slot * 8] = lo;
            }
        }
        __syncthreads();

        // ---------- compute: 48 MFMAs per wave ----------
        const int frswz = (lr >> 1) & 3;
        f16x8 bhf[4], blf[4];
        #pragma unroll
        for (int fn = 0; fn < 4; ++fn) {
            int noff = (wc * 64 + fn * 16 + lr) * 32 + (ls ^ frswz) * 8;
            bhf[fn] = *(const f16x8*)&sBh[noff];
            blf[fn] = *(const f16x8*)&sBl[noff];
        }
        #pragma unroll
        for (int fm = 0; fm < 4; ++fm) {
            int moff = (wr * 64 + fm * 16 + lr) * 32 + (ls ^ frswz) * 8;
            f16x8 ah = *(const f16x8*)&sAh[moff];
            f16x8 al = *(const f16x8*)&sAl[moff];
            #pragma unroll
            for (int fn = 0; fn < 4; ++fn) {
                acc1[fm][fn] = __builtin_amdgcn_mfma_f32_16x16x32_f16(ah, bhf[fn], acc1[fm][fn], 0, 0, 0);
                acc2[fm][fn] = __builtin_amdgcn_mfma_f32_16x16x32_f16(ah, blf[fn], acc2[fm][fn], 0, 0, 0);
                acc2[fm][fn] = __builtin_amdgcn_mfma_f32_16x16x32_f16(al, bhf[fn], acc2[fm][fn], 0, 0, 0);
            }
        }
        __syncthreads();
    }

    // ---------- epilogue ----------
    const float inv = 1.f / 4096.f;
    #pragma unroll
    for (int fn = 0; fn < 4; ++fn) {
        int gcol = col0 + wc * 64 + fn * 16 + lr;
        if (gcol >= N) continue;
        float bv = bias[gcol];
        #pragma unroll
        for (int fm = 0; fm < 4; ++fm) {
            int growb = row0 + wr * 64 + fm * 16 + ls * 4;
            #pragma unroll
            for (int r = 0; r < 4; ++r) {
                int grow = growb + r;
                if (grow >= M) continue;
                float val = acc1[fm][fn][r] + acc2[fm][fn][r] * inv + bv;
                if (MODE == 0) {
                    val = fmaxf(val, 0.f);
                    half_t h = (half_t)val;
                    half_t l2 = (half_t)((val - (float)h) * 4096.f);
                    union { half_t h; unsigned short u; } uh, ul;
                    uh.h = h; ul.h = l2;
                    ((unsigned*)Cout)[(size_t)grow * N + gcol] =
                        ((unsigned)ul.u << 16) | (unsigned)uh.u;
                } else {
                    ((float*)Cout)[(size_t)grow * N + gcol] = val;
                }
            }
        }
    }
}

// ---------------------------------------------------------------------------
// BN stats: per-column sum and sumsq
// ---------------------------------------------------------------------------
__global__ __launch_bounds__(320) void k_bn_stats(const float* __restrict__ h2,
                                                  float* __restrict__ stats, int N) {
    int c = threadIdx.x;
    if (c >= EMB) return;
    int rpb = (N + gridDim.x - 1) / gridDim.x;
    int r0 = blockIdx.x * rpb;
    int r1 = min(N, r0 + rpb);
    float s = 0.f, q = 0.f;
    for (int r = r0; r < r1; ++r) {
        float v = h2[(size_t)r * EMB + c];
        s += v;
        q = fmaf(v, v, q);
    }
    atomicAdd(&stats[c], s);
    atomicAdd(&stats[EMB + c], q);
}

__global__ void k_bn_finalize(float* __restrict__ stats, const float* __restrict__ gamma,
                              const float* __restrict__ beta, int N) {
    int c = threadIdx.x;
    if (c >= EMB) return;
    float inv_n = 1.f / (float)N;
    float mu = stats[c] * inv_n;
    float var = stats[EMB + c] * inv_n - mu * mu;
    float sc = gamma[c] * rsqrtf(var + EPS);
    stats[2 * EMB + c] = sc;
    stats[3 * EMB + c] = beta[c] - mu * sc;
}

__global__ void k_bn_apply(const float* __restrict__ h2, const float* __restrict__ stats,
                           float* __restrict__ h, int N, int relu) {
    const float4* x4 = (const float4*)h2;
    float4* o4 = (float4*)h;
    const float4* sc4 = (const float4*)(stats + 2 * EMB);
    const float4* sh4 = (const float4*)(stats + 3 * EMB);
    int total = N * EMB4;
    for (int i = blockIdx.x * blockDim.x + threadIdx.x; i < total;
         i += gridDim.x * blockDim.x) {
        int c = i % EMB4;
        float4 v = x4[i], s = sc4[c], t = sh4[c];
        float4 r;
        r.x = fmaf(v.x, s.x, t.x);
        r.y = fmaf(v.y, s.y, t.y);
        r.z = fmaf(v.z, s.z, t.z);
        r.w = fmaf(v.w, s.w, t.w);
        if (relu) {
            r.x = fmaxf(r.x, 0.f); r.y = fmaxf(r.y, 0.f);
            r.z = fmaxf(r.z, 0.f); r.w = fmaxf(r.w, 0.f);
        }
        o4[i] = r;
    }
}

// ---------------------------------------------------------------------------
extern "C" void kernel_launch(void* const* d_in, const int* in_sizes, int n_in,
                              void* d_out, int out_size, void* d_ws, size_t ws_size,
                              hipStream_t stream) {
    const int*   x      = (const int*)d_in[0];
    const int*   ei     = (const int*)d_in[1];
    const int*   ea     = (const int*)d_in[2];
    const float* x_emb1 = (const float*)d_in[3];
    const float* x_emb2 = (const float*)d_in[4];
    const float* e1     = (const float*)d_in[5];
    const float* e2     = (const float*)d_in[6];
    const float* W1     = (const float*)d_in[7];
    const float* b1     = (const float*)d_in[8];
    const float* W2     = (const float*)d_in[9];
    const float* b2     = (const float*)d_in[10];
    const float* gamma  = (const float*)d_in[11];
    const float* beta   = (const float*)d_in[12];
    float* out = (float*)d_out;

    int N = in_sizes[0] / 2;
    int E = in_sizes[2] / 2;
    int L = in_sizes[7] / (EMB * 2 * EMB);

    // ws layout (floats): stats @0 (1216) | start @1216 (50001 ints) |
    // packed @51220 (E ints) | agg @ aligned (N*EMB) | hm (N*600 u32)
    // deg/cursor alias the agg region (dead until first k_agg_csr).
    float* ws    = (float*)d_ws;
    float* stats = ws;
    int*   startA = (int*)(ws + 1216);
    int*   packed = (int*)(ws + 1216 + 50004);
    size_t agg_ofs = 1216 + 50004 + (size_t)E;
    agg_ofs = (agg_ofs + 7) & ~(size_t)7;          // 32B align
    float* agg = ws + agg_ofs;
    unsigned* hm = (unsigned*)(agg + (size_t)N * EMB);
    int* deg    = (int*)agg;
    int* cursor = deg + 50004;

    // weight planes live in d_out's dead window (between agg and bn_apply)
    half_t* b1h = (half_t*)d_out;
    half_t* b1l = b1h + (size_t)600 * 320;
    half_t* b2h = (half_t*)d_out;
    half_t* b2l = b2h + (size_t)300 * 608;

    // ---- one-time: CSR build + h init ----
    k_zero<<<(N + 256) / 256, 256, 0, stream>>>(deg, N + 1);
    k_hist<<<1024, 256, 0, stream>>>(ei, deg, E);
    k_prefix<<<1, 1024, 0, stream>>>(deg, startA, cursor, N);
    k_permute<<<1024, 256, 0, stream>>>(ei, ea, cursor, packed, E);
    k_hinit<<<2048, 256, 0, stream>>>(x, x_emb1, x_emb2, out, N);

    int rowblks = (N + 127) / 128;
    for (int l = 0; l < L; ++l) {
        const float* e1l = e1 + (size_t)l * 6 * EMB;
        const float* e2l = e2 + (size_t)l * 3 * EMB;

        k_agg_csr<<<(N + 3) / 4, 256, 0, stream>>>(startA, packed, out, e1l, e2l,
                                                   agg, stats, N);

        // h (d_out) is dead from here until bn_apply -> borrow for weight planes
        k_cvtB<<<128, 256, 0, stream>>>(W1 + (size_t)l * EMB * 2 * EMB,
                                        b1h, b1l, EMB, 2 * EMB, 320);
        dim3 g1(5, rowblks);
        k_mfma_gemm<0><<<g1, 256, 0, stream>>>(
            agg, b1h, b1l, b1 + (size_t)l * 2 * EMB, hm, N, 2 * EMB, EMB, 320);

        k_cvtB<<<128, 256, 0, stream>>>(W2 + (size_t)l * 2 * EMB * EMB,
                                        b2h, b2l, 2 * EMB, EMB, 608);
        dim3 g2(3, rowblks);
        k_mfma_gemm<1><<<g2, 256, 0, stream>>>(
            hm, b2h, b2l, b2 + (size_t)l * EMB, agg, N, EMB, 2 * EMB, 608);

        k_bn_stats<<<250, 320, 0, stream>>>(agg, stats, N);
        k_bn_finalize<<<1, 320, 0, stream>>>(stats, gamma + (size_t)l * EMB,
                                             beta + (size_t)l * EMB, N);
        k_bn_apply<<<2048, 256, 0, stream>>>(agg, stats, out, N, (l < L - 1) ? 1 : 0);
    }
}

// Round 7
// 2315.870 us; speedup vs baseline: 2.1552x; 1.3630x over previous
//
#include <hip/hip_runtime.h>

#define EMB 300
#define EMB4 75
#define EPS 1e-5f

typedef _Float16 half_t;
using f16x8 = __attribute__((ext_vector_type(8))) _Float16;
using f32x4 = __attribute__((ext_vector_type(4))) float;

__device__ __forceinline__ float4 f4add(float4 a, float4 b) {
    return make_float4(a.x + b.x, a.y + b.y, a.z + b.z, a.w + b.w);
}

// ---------------------------------------------------------------------------
// h = x_emb1[x[:,0]] + x_emb2[x[:,1]]
// ---------------------------------------------------------------------------
__global__ void k_hinit(const int* __restrict__ x, const float* __restrict__ emb1,
                        const float* __restrict__ emb2, float* __restrict__ h, int N) {
    int total = N * EMB4;
    for (int i = blockIdx.x * blockDim.x + threadIdx.x; i < total;
         i += gridDim.x * blockDim.x) {
        int node = i / EMB4;
        int c = i - node * EMB4;
        int x0 = x[node * 2], x1 = x[node * 2 + 1];
        float4 va = ((const float4*)emb1)[x0 * EMB4 + c];
        float4 vb = ((const float4*)emb2)[x1 * EMB4 + c];
        ((float4*)h)[i] = f4add(va, vb);
    }
}

// ---------------------------------------------------------------------------
// CSR build (once per call): histogram -> prefix scan -> permute
// packed[e] = src_row | (edge_type << 20)
// ---------------------------------------------------------------------------
__global__ void k_zero(int* __restrict__ p, int n) {
    for (int i = blockIdx.x * blockDim.x + threadIdx.x; i < n;
         i += gridDim.x * blockDim.x) p[i] = 0;
}

__global__ void k_hist(const int* __restrict__ ei, int* __restrict__ deg, int E) {
    for (int e = blockIdx.x * blockDim.x + threadIdx.x; e < E;
         e += gridDim.x * blockDim.x) atomicAdd(&deg[ei[E + e]], 1);
}

__global__ __launch_bounds__(1024) void k_prefix(const int* __restrict__ deg,
                                                 int* __restrict__ start,
                                                 int* __restrict__ cursor, int N) {
    __shared__ int part[1024];
    int tid = threadIdx.x;
    int per = (N + 1023) / 1024;
    int i0 = tid * per;
    int i1 = min(N, i0 + per);
    int s = 0;
    for (int i = i0; i < i1; ++i) s += deg[i];
    part[tid] = s;
    __syncthreads();
    for (int off = 1; off < 1024; off <<= 1) {
        int v = (tid >= off) ? part[tid - off] : 0;
        __syncthreads();
        part[tid] += v;
        __syncthreads();
    }
    int base = (tid == 0) ? 0 : part[tid - 1];
    for (int i = i0; i < i1; ++i) {
        start[i] = base;
        cursor[i] = base;
        base += deg[i];
    }
    if (tid == 1023) start[N] = part[1023];
}

__global__ void k_permute(const int* __restrict__ ei, const int* __restrict__ ea,
                          int* __restrict__ cursor, int* __restrict__ packed, int E) {
    for (int e = blockIdx.x * blockDim.x + threadIdx.x; e < E;
         e += gridDim.x * blockDim.x) {
        int col = ei[E + e];
        int pos = atomicAdd(&cursor[col], 1);
        int t = ea[2 * e] * 3 + ea[2 * e + 1];
        packed[pos] = ei[e] | (t << 20);
    }
}

// ---------------------------------------------------------------------------
// CSR aggregation: one wave per destination node, accumulators in registers.
// agg[i] = h[i] + self_combo + sum_{e: col=i} (h[row_e] + comb[t_e])
// Self-loop attr (4,0) -> combo index 12. Block 0 zeroes BN stats.
// ---------------------------------------------------------------------------
__global__ __launch_bounds__(256) void k_agg_csr(
    const int* __restrict__ start, const int* __restrict__ packed,
    const float* __restrict__ h, const float* __restrict__ e1l,
    const float* __restrict__ e2l, float* __restrict__ agg,
    float* __restrict__ stats, int N) {
    __shared__ float sc[18 * EMB];
    for (int i = threadIdx.x; i < 18 * EMB; i += blockDim.x) {
        int t = i / EMB, c = i - t * EMB;
        sc[i] = e1l[(t / 3) * EMB + c] + e2l[(t % 3) * EMB + c];
    }
    if (blockIdx.x == 0) {
        for (int j = threadIdx.x; j < 2 * EMB; j += blockDim.x) stats[j] = 0.f;
    }
    __syncthreads();

    int lane = threadIdx.x & 63;
    int node = blockIdx.x * 4 + (threadIdx.x >> 6);
    if (node >= N) return;

    const bool has1 = lane < (EMB4 - 64);   // lanes 0..10 own chunks 64..74
    const float4* hp = (const float4*)(h + (size_t)node * EMB);
    const float4* scp = (const float4*)(sc + 12 * EMB);
    float4 a0 = f4add(hp[lane], scp[lane]);
    float4 a1;
    if (has1) a1 = f4add(hp[lane + 64], scp[lane + 64]);

    int s0 = start[node], s1 = start[node + 1];
    for (int e = s0; e < s1; ++e) {
        int p = __builtin_amdgcn_readfirstlane(packed[e]);
        int row = p & 0xFFFFF;
        int t = p >> 20;
        const float4* hr = (const float4*)(h + (size_t)row * EMB);
        const float4* cr = (const float4*)(sc + t * EMB);
        a0 = f4add(a0, f4add(hr[lane], cr[lane]));
        if (has1) a1 = f4add(a1, f4add(hr[lane + 64], cr[lane + 64]));
    }
    float4* ap = (float4*)(agg + (size_t)node * EMB);
    ap[lane] = a0;
    if (has1) ap[lane + 64] = a1;
}

// ---------------------------------------------------------------------------
// Weight pre-transpose + fp16-split conversion:
// W [K][N] fp32 -> Bt_hi/Bt_lo [N][Kpad] f16; lo = UNSCALED residual v-fp16(v)
// (single-accumulator split-GEMM: all three MFMA products share one acc)
// ---------------------------------------------------------------------------
__global__ void k_cvtB(const float* __restrict__ W, half_t* __restrict__ bh,
                       half_t* __restrict__ bl, int K, int N, int Kpad) {
    int cpr = Kpad >> 3;
    int total = N * cpr;
    for (int i = blockIdx.x * blockDim.x + threadIdx.x; i < total;
         i += gridDim.x * blockDim.x) {
        int n = i / cpr;
        int ch = i - n * cpr;
        f16x8 hi, lo;
        #pragma unroll
        for (int j = 0; j < 8; ++j) {
            int k = ch * 8 + j;
            float v = (k < K) ? W[(size_t)k * N + n] : 0.f;
            half_t h = (half_t)v;
            hi[j] = h;
            lo[j] = (half_t)(v - (float)h);
        }
        *(f16x8*)&bh[(size_t)n * Kpad + ch * 8] = hi;
        *(f16x8*)&bl[(size_t)n * Kpad + ch * 8] = lo;
    }
}

// ---------------------------------------------------------------------------
// Split-fp16 MFMA GEMM: C = op(A @ B^T_planes + bias)
// 128x128 tile, BK=32, 256 threads = 4 waves (2x2), 64x64 per wave.
// Single f32x4 acc per fragment (lo planes hold unscaled residuals):
//   acc += hi*hi + hi*lo + lo*hi   -> 64 AGPR/wave (was 128; occupancy 2x).
// MODE 0: A fp32 [M][K] (convert in staging), OUT packed u32(res16|hi16), ReLU.
// MODE 1: A packed u32 [M][K],                OUT fp32, no ReLU.
// LDS swizzle: 16B-slot index ^= (row>>1)&3  (uniform bank groups, verified).
// ---------------------------------------------------------------------------
template <int MODE>
__global__ __launch_bounds__(256, 2) void k_mfma_gemm(
    const void* __restrict__ Ain,
    const half_t* __restrict__ Bh, const half_t* __restrict__ Bl,
    const float* __restrict__ bias, void* __restrict__ Cout,
    int M, int N, int K, int Kpad)
{
    __shared__ half_t sAh[128 * 32], sAl[128 * 32], sBh[128 * 32], sBl[128 * 32];
    const int tid = threadIdx.x;
    const int lane = tid & 63, wid = tid >> 6;
    const int lr = lane & 15, ls = lane >> 4;
    const int wr = wid >> 1, wc = wid & 1;
    const int row0 = blockIdx.y * 128, col0 = blockIdx.x * 128;

    const int sm = tid >> 1;
    const int kh = tid & 1;
    size_t arow = row0 + sm; if (arow >= (size_t)M) arow = M - 1;
    const int aswz = (sm >> 1) & 3;

    f32x4 acc[4][4];
    #pragma unroll
    for (int i = 0; i < 4; ++i)
        #pragma unroll
        for (int j = 0; j < 4; ++j)
            acc[i][j] = (f32x4){0.f, 0.f, 0.f, 0.f};

    const int nsteps = Kpad / 32;
    for (int s = 0; s < nsteps; ++s) {
        const int k0 = s * 32;

        // ---------- stage B: async global->LDS, pre-swizzled source ----------
        #pragma unroll
        for (int jj = 0; jj < 2; ++jj) {
            int j = wid * 2 + jj;
            int nl = j * 16 + (lane >> 2);
            int t = lane & 3;
            int ch = t ^ ((nl >> 1) & 3);
            size_t brow = col0 + nl; if (brow >= (size_t)N) brow = N - 1;
            const half_t* gh = Bh + brow * Kpad + k0 + ch * 8;
            const half_t* gl = Bl + brow * Kpad + k0 + ch * 8;
            __builtin_amdgcn_global_load_lds(
                (const __attribute__((address_space(1))) void*)gh,
                (__attribute__((address_space(3))) void*)&sBh[j * 512], 16, 0, 0);
            __builtin_amdgcn_global_load_lds(
                (const __attribute__((address_space(1))) void*)gl,
                (__attribute__((address_space(3))) void*)&sBl[j * 512], 16, 0, 0);
        }

        // ---------- stage A ----------
        if (MODE == 0) {
            const float* A = (const float*)Ain;
            const float* ap = A + arow * K;
            float va[16];
            #pragma unroll
            for (int q = 0; q < 4; ++q) {
                int gk = k0 + kh * 16 + q * 4;
                float4 v = make_float4(0.f, 0.f, 0.f, 0.f);
                if (gk < K) v = *(const float4*)(ap + gk);
                va[q * 4 + 0] = v.x; va[q * 4 + 1] = v.y;
                va[q * 4 + 2] = v.z; va[q * 4 + 3] = v.w;
            }
            #pragma unroll
            for (int c = 0; c < 2; ++c) {
                f16x8 hi, lo;
                #pragma unroll
                for (int j = 0; j < 8; ++j) {
                    float xv = va[c * 8 + j];
                    half_t h = (half_t)xv;
                    hi[j] = h;
                    lo[j] = (half_t)(xv - (float)h);
                }
                int slot = (kh * 2 + c) ^ aswz;
                *(f16x8*)&sAh[sm * 32 + slot * 8] = hi;
                *(f16x8*)&sAl[sm * 32 + slot * 8] = lo;
            }
        } else {
            const unsigned* A = (const unsigned*)Ain;
            #pragma unroll
            for (int c = 0; c < 2; ++c) {
                int u = kh * 2 + c;
                int gk = k0 + u * 8;
                f16x8 hi, lo;
                if (gk < K) {
                    const unsigned* p = A + arow * K + gk;
                    uint4 w0 = *(const uint4*)p;
                    uint4 w1 = *(const uint4*)(p + 4);
                    unsigned wv[8] = {w0.x, w0.y, w0.z, w0.w, w1.x, w1.y, w1.z, w1.w};
                    #pragma unroll
                    for (int j = 0; j < 8; ++j) {
                        union { unsigned short u16; half_t h; } a, b;
                        a.u16 = (unsigned short)(wv[j] & 0xffffu);
                        b.u16 = (unsigned short)(wv[j] >> 16);
                        hi[j] = a.h; lo[j] = b.h;
                    }
                } else {
                    #pragma unroll
                    for (int j = 0; j < 8; ++j) { hi[j] = (half_t)0.f; lo[j] = (half_t)0.f; }
                }
                int slot = u ^ aswz;
                *(f16x8*)&sAh[sm * 32 + slot * 8] = hi;
                *(f16x8*)&sAl[sm * 32 + slot * 8] = lo;
            }
        }
        __syncthreads();

        // ---------- compute: 48 MFMAs per wave, one acc per fragment ----------
        const int frswz = (lr >> 1) & 3;
        f16x8 bhf[4], blf[4];
        #pragma unroll
        for (int fn = 0; fn < 4; ++fn) {
            int noff = (wc * 64 + fn * 16 + lr) * 32 + (ls ^ frswz) * 8;
            bhf[fn] = *(const f16x8*)&sBh[noff];
            blf[fn] = *(const f16x8*)&sBl[noff];
        }
        #pragma unroll
        for (int fm = 0; fm < 4; ++fm) {
            int moff = (wr * 64 + fm * 16 + lr) * 32 + (ls ^ frswz) * 8;
            f16x8 ah = *(const f16x8*)&sAh[moff];
            f16x8 al = *(const f16x8*)&sAl[moff];
            #pragma unroll
            for (int fn = 0; fn < 4; ++fn) {
                acc[fm][fn] = __builtin_amdgcn_mfma_f32_16x16x32_f16(ah, bhf[fn], acc[fm][fn], 0, 0, 0);
                acc[fm][fn] = __builtin_amdgcn_mfma_f32_16x16x32_f16(ah, blf[fn], acc[fm][fn], 0, 0, 0);
                acc[fm][fn] = __builtin_amdgcn_mfma_f32_16x16x32_f16(al, bhf[fn], acc[fm][fn], 0, 0, 0);
            }
        }
        __syncthreads();
    }

    // ---------- epilogue ----------
    #pragma unroll
    for (int fn = 0; fn < 4; ++fn) {
        int gcol = col0 + wc * 64 + fn * 16 + lr;
        if (gcol >= N) continue;
        float bv = bias[gcol];
        #pragma unroll
        for (int fm = 0; fm < 4; ++fm) {
            int growb = row0 + wr * 64 + fm * 16 + ls * 4;
            #pragma unroll
            for (int r = 0; r < 4; ++r) {
                int grow = growb + r;
                if (grow >= M) continue;
                float val = acc[fm][fn][r] + bv;
                if (MODE == 0) {
                    val = fmaxf(val, 0.f);
                    half_t h = (half_t)val;
                    half_t l2 = (half_t)(val - (float)h);
                    union { half_t h; unsigned short u; } uh, ul;
                    uh.h = h; ul.h = l2;
                    ((unsigned*)Cout)[(size_t)grow * N + gcol] =
                        ((unsigned)ul.u << 16) | (unsigned)uh.u;
                } else {
                    ((float*)Cout)[(size_t)grow * N + gcol] = val;
                }
            }
        }
    }
}

// ---------------------------------------------------------------------------
// BN stats: per-column sum and sumsq
// ---------------------------------------------------------------------------
__global__ __launch_bounds__(320) void k_bn_stats(const float* __restrict__ h2,
                                                  float* __restrict__ stats, int N) {
    int c = threadIdx.x;
    if (c >= EMB) return;
    int rpb = (N + gridDim.x - 1) / gridDim.x;
    int r0 = blockIdx.x * rpb;
    int r1 = min(N, r0 + rpb);
    float s = 0.f, q = 0.f;
    for (int r = r0; r < r1; ++r) {
        float v = h2[(size_t)r * EMB + c];
        s += v;
        q = fmaf(v, v, q);
    }
    atomicAdd(&stats[c], s);
    atomicAdd(&stats[EMB + c], q);
}

__global__ void k_bn_finalize(float* __restrict__ stats, const float* __restrict__ gamma,
                              const float* __restrict__ beta, int N) {
    int c = threadIdx.x;
    if (c >= EMB) return;
    float inv_n = 1.f / (float)N;
    float mu = stats[c] * inv_n;
    float var = stats[EMB + c] * inv_n - mu * mu;
    float sc = gamma[c] * rsqrtf(var + EPS);
    stats[2 * EMB + c] = sc;
    stats[3 * EMB + c] = beta[c] - mu * sc;
}

__global__ void k_bn_apply(const float* __restrict__ h2, const float* __restrict__ stats,
                           float* __restrict__ h, int N, int relu) {
    const float4* x4 = (const float4*)h2;
    float4* o4 = (float4*)h;
    const float4* sc4 = (const float4*)(stats + 2 * EMB);
    const float4* sh4 = (const float4*)(stats + 3 * EMB);
    int total = N * EMB4;
    for (int i = blockIdx.x * blockDim.x + threadIdx.x; i < total;
         i += gridDim.x * blockDim.x) {
        int c = i % EMB4;
        float4 v = x4[i], s = sc4[c], t = sh4[c];
        float4 r;
        r.x = fmaf(v.x, s.x, t.x);
        r.y = fmaf(v.y, s.y, t.y);
        r.z = fmaf(v.z, s.z, t.z);
        r.w = fmaf(v.w, s.w, t.w);
        if (relu) {
            r.x = fmaxf(r.x, 0.f); r.y = fmaxf(r.y, 0.f);
            r.z = fmaxf(r.z, 0.f); r.w = fmaxf(r.w, 0.f);
        }
        o4[i] = r;
    }
}

// ---------------------------------------------------------------------------
extern "C" void kernel_launch(void* const* d_in, const int* in_sizes, int n_in,
                              void* d_out, int out_size, void* d_ws, size_t ws_size,
                              hipStream_t stream) {
    const int*   x      = (const int*)d_in[0];
    const int*   ei     = (const int*)d_in[1];
    const int*   ea     = (const int*)d_in[2];
    const float* x_emb1 = (const float*)d_in[3];
    const float* x_emb2 = (const float*)d_in[4];
    const float* e1     = (const float*)d_in[5];
    const float* e2     = (const float*)d_in[6];
    const float* W1     = (const float*)d_in[7];
    const float* b1     = (const float*)d_in[8];
    const float* W2     = (const float*)d_in[9];
    const float* b2     = (const float*)d_in[10];
    const float* gamma  = (const float*)d_in[11];
    const float* beta   = (const float*)d_in[12];
    float* out = (float*)d_out;

    int N = in_sizes[0] / 2;
    int E = in_sizes[2] / 2;
    int L = in_sizes[7] / (EMB * 2 * EMB);

    // ws layout (floats): stats @0 (1216) | start @1216 (50001 ints) |
    // packed @51220 (E ints) | agg @ aligned (N*EMB) | hm (N*600 u32)
    // deg/cursor alias the agg region (dead until first k_agg_csr).
    float* ws    = (float*)d_ws;
    float* stats = ws;
    int*   startA = (int*)(ws + 1216);
    int*   packed = (int*)(ws + 1216 + 50004);
    size_t agg_ofs = 1216 + 50004 + (size_t)E;
    agg_ofs = (agg_ofs + 7) & ~(size_t)7;          // 32B align
    float* agg = ws + agg_ofs;
    unsigned* hm = (unsigned*)(agg + (size_t)N * EMB);
    int* deg    = (int*)agg;
    int* cursor = deg + 50004;

    // weight planes live in d_out's dead window (between agg and bn_apply)
    half_t* b1h = (half_t*)d_out;
    half_t* b1l = b1h + (size_t)600 * 320;
    half_t* b2h = (half_t*)d_out;
    half_t* b2l = b2h + (size_t)300 * 608;

    // ---- one-time: CSR build + h init ----
    k_zero<<<(N + 256) / 256, 256, 0, stream>>>(deg, N + 1);
    k_hist<<<1024, 256, 0, stream>>>(ei, deg, E);
    k_prefix<<<1, 1024, 0, stream>>>(deg, startA, cursor, N);
    k_permute<<<1024, 256, 0, stream>>>(ei, ea, cursor, packed, E);
    k_hinit<<<2048, 256, 0, stream>>>(x, x_emb1, x_emb2, out, N);

    int rowblks = (N + 127) / 128;
    for (int l = 0; l < L; ++l) {
        const float* e1l = e1 + (size_t)l * 6 * EMB;
        const float* e2l = e2 + (size_t)l * 3 * EMB;

        k_agg_csr<<<(N + 3) / 4, 256, 0, stream>>>(startA, packed, out, e1l, e2l,
                                                   agg, stats, N);

        // h (d_out) is dead from here until bn_apply -> borrow for weight planes
        k_cvtB<<<128, 256, 0, stream>>>(W1 + (size_t)l * EMB * 2 * EMB,
                                        b1h, b1l, EMB, 2 * EMB, 320);
        dim3 g1(5, rowblks);
        k_mfma_gemm<0><<<g1, 256, 0, stream>>>(
            agg, b1h, b1l, b1 + (size_t)l * 2 * EMB, hm, N, 2 * EMB, EMB, 320);

        k_cvtB<<<128, 256, 0, stream>>>(W2 + (size_t)l * 2 * EMB * EMB,
                                        b2h, b2l, 2 * EMB, EMB, 608);
        dim3 g2(3, rowblks);
        k_mfma_gemm<1><<<g2, 256, 0, stream>>>(
            hm, b2h, b2l, b2 + (size_t)l * EMB, agg, N, EMB, 2 * EMB, 608);

        k_bn_stats<<<250, 320, 0, stream>>>(agg, stats, N);
        k_bn_finalize<<<1, 320, 0, stream>>>(stats, gamma + (size_t)l * EMB,
                                             beta + (size_t)l * EMB, N);
        k_bn_apply<<<2048, 256, 0, stream>>>(agg, stats, out, N, (l < L - 1) ? 1 : 0);
    }
}

// Round 10
// 2123.647 us; speedup vs baseline: 2.3503x; 1.0905x over previous
//
#include <hip/hip_runtime.h>

#define EMB 300
#define EMB4 75
#define EPS 1e-5f

typedef _Float16 half_t;
using f16x8 = __attribute__((ext_vector_type(8))) _Float16;
using f32x4 = __attribute__((ext_vector_type(4))) float;

__device__ __forceinline__ float4 f4add(float4 a, float4 b) {
    return make_float4(a.x + b.x, a.y + b.y, a.z + b.z, a.w + b.w);
}

// ---------------------------------------------------------------------------
// h = x_emb1[x[:,0]] + x_emb2[x[:,1]]
// ---------------------------------------------------------------------------
__global__ void k_hinit(const int* __restrict__ x, const float* __restrict__ emb1,
                        const float* __restrict__ emb2, float* __restrict__ h, int N) {
    int total = N * EMB4;
    for (int i = blockIdx.x * blockDim.x + threadIdx.x; i < total;
         i += gridDim.x * blockDim.x) {
        int node = i / EMB4;
        int c = i - node * EMB4;
        int x0 = x[node * 2], x1 = x[node * 2 + 1];
        float4 va = ((const float4*)emb1)[x0 * EMB4 + c];
        float4 vb = ((const float4*)emb2)[x1 * EMB4 + c];
        ((float4*)h)[i] = f4add(va, vb);
    }
}

// ---------------------------------------------------------------------------
// CSR build (once per call): histogram -> prefix scan -> permute
// packed[e] = src_row | (edge_type << 20)
// ---------------------------------------------------------------------------
__global__ void k_zero(int* __restrict__ p, int n) {
    for (int i = blockIdx.x * blockDim.x + threadIdx.x; i < n;
         i += gridDim.x * blockDim.x) p[i] = 0;
}

__global__ void k_hist(const int* __restrict__ ei, int* __restrict__ deg, int E) {
    for (int e = blockIdx.x * blockDim.x + threadIdx.x; e < E;
         e += gridDim.x * blockDim.x) atomicAdd(&deg[ei[E + e]], 1);
}

__global__ __launch_bounds__(1024) void k_prefix(const int* __restrict__ deg,
                                                 int* __restrict__ start,
                                                 int* __restrict__ cursor, int N) {
    __shared__ int part[1024];
    int tid = threadIdx.x;
    int per = (N + 1023) / 1024;
    int i0 = tid * per;
    int i1 = min(N, i0 + per);
    int s = 0;
    for (int i = i0; i < i1; ++i) s += deg[i];
    part[tid] = s;
    __syncthreads();
    for (int off = 1; off < 1024; off <<= 1) {
        int v = (tid >= off) ? part[tid - off] : 0;
        __syncthreads();
        part[tid] += v;
        __syncthreads();
    }
    int base = (tid == 0) ? 0 : part[tid - 1];
    for (int i = i0; i < i1; ++i) {
        start[i] = base;
        cursor[i] = base;
        base += deg[i];
    }
    if (tid == 1023) start[N] = part[1023];
}

__global__ void k_permute(const int* __restrict__ ei, const int* __restrict__ ea,
                          int* __restrict__ cursor, int* __restrict__ packed, int E) {
    for (int e = blockIdx.x * blockDim.x + threadIdx.x; e < E;
         e += gridDim.x * blockDim.x) {
        int col = ei[E + e];
        int pos = atomicAdd(&cursor[col], 1);
        int t = ea[2 * e] * 3 + ea[2 * e + 1];
        packed[pos] = ei[e] | (t << 20);
    }
}

// ---------------------------------------------------------------------------
// CSR aggregation: one wave per destination node, accumulators in registers.
// agg[i] = h[i] + self_combo + sum_{e: col=i} (h[row_e] + comb[t_e])
// Self-loop attr (4,0) -> combo index 12. Block 0 zeroes BN stats.
// ---------------------------------------------------------------------------
__global__ __launch_bounds__(256) void k_agg_csr(
    const int* __restrict__ start, const int* __restrict__ packed,
    const float* __restrict__ h, const float* __restrict__ e1l,
    const float* __restrict__ e2l, float* __restrict__ agg,
    float* __restrict__ stats, int N) {
    __shared__ float sc[18 * EMB];
    for (int i = threadIdx.x; i < 18 * EMB; i += blockDim.x) {
        int t = i / EMB, c = i - t * EMB;
        sc[i] = e1l[(t / 3) * EMB + c] + e2l[(t % 3) * EMB + c];
    }
    if (blockIdx.x == 0) {
        for (int j = threadIdx.x; j < 2 * EMB; j += blockDim.x) stats[j] = 0.f;
    }
    __syncthreads();

    int lane = threadIdx.x & 63;
    int node = blockIdx.x * 4 + (threadIdx.x >> 6);
    if (node >= N) return;

    const bool has1 = lane < (EMB4 - 64);   // lanes 0..10 own chunks 64..74
    const float4* hp = (const float4*)(h + (size_t)node * EMB);
    const float4* scp = (const float4*)(sc + 12 * EMB);
    float4 a0 = f4add(hp[lane], scp[lane]);
    float4 a1;
    if (has1) a1 = f4add(hp[lane + 64], scp[lane + 64]);

    int s0 = start[node], s1 = start[node + 1];
    for (int e = s0; e < s1; ++e) {
        int p = __builtin_amdgcn_readfirstlane(packed[e]);
        int row = p & 0xFFFFF;
        int t = p >> 20;
        const float4* hr = (const float4*)(h + (size_t)row * EMB);
        const float4* cr = (const float4*)(sc + t * EMB);
        a0 = f4add(a0, f4add(hr[lane], cr[lane]));
        if (has1) a1 = f4add(a1, f4add(hr[lane + 64], cr[lane + 64]));
    }
    float4* ap = (float4*)(agg + (size_t)node * EMB);
    ap[lane] = a0;
    if (has1) ap[lane + 64] = a1;
}

// ---------------------------------------------------------------------------
// Weight pre-transpose + fp16-split conversion:
// W [K][N] fp32 -> Bt_hi/Bt_lo [N][Kpad] f16; lo = UNSCALED residual v-fp16(v)
// ---------------------------------------------------------------------------
__global__ void k_cvtB(const float* __restrict__ W, half_t* __restrict__ bh,
                       half_t* __restrict__ bl, int K, int N, int Kpad) {
    int cpr = Kpad >> 3;
    int total = N * cpr;
    for (int i = blockIdx.x * blockDim.x + threadIdx.x; i < total;
         i += gridDim.x * blockDim.x) {
        int n = i / cpr;
        int ch = i - n * cpr;
        f16x8 hi, lo;
        #pragma unroll
        for (int j = 0; j < 8; ++j) {
            int k = ch * 8 + j;
            float v = (k < K) ? W[(size_t)k * N + n] : 0.f;
            half_t h = (half_t)v;
            hi[j] = h;
            lo[j] = (half_t)(v - (float)h);
        }
        *(f16x8*)&bh[(size_t)n * Kpad + ch * 8] = hi;
        *(f16x8*)&bl[(size_t)n * Kpad + ch * 8] = lo;
    }
}

// ---------------------------------------------------------------------------
// Split-fp16 MFMA GEMM: C = op(A @ B^T_planes + bias)
// 128x128 tile, BK=32, 256 threads = 4 waves (2x2), 64x64 per wave.
// Single f32x4 acc per fragment: acc += hi*hi + hi*lo + lo*hi (64 AGPR).
// __launch_bounds__(256,3): 132 unified regs fits 3 waves/SIMD (512/132=3.9);
// LDS 32KB allows 5 blocks/CU -> 3 blocks/CU target occupancy.
// MODE 0: A fp32 [M][K] (convert in staging), OUT packed u32(res16|hi16), ReLU.
// MODE 1: A packed u32 [M][K], OUT fp32, no ReLU; epilogue fuses BN column
//         stats (sum, sumsq) via shfl-reduce + atomics into stats[].
// LDS swizzle: 16B-slot index ^= (row>>1)&3  (uniform bank groups, verified).
// ---------------------------------------------------------------------------
template <int MODE>
__global__ __launch_bounds__(256, 3) void k_mfma_gemm(
    const void* __restrict__ Ain,
    const half_t* __restrict__ Bh, const half_t* __restrict__ Bl,
    const float* __restrict__ bias, void* __restrict__ Cout,
    float* __restrict__ stats,
    int M, int N, int K, int Kpad)
{
    __shared__ half_t sAh[128 * 32], sAl[128 * 32], sBh[128 * 32], sBl[128 * 32];
    const int tid = threadIdx.x;
    const int lane = tid & 63, wid = tid >> 6;
    const int lr = lane & 15, ls = lane >> 4;
    const int wr = wid >> 1, wc = wid & 1;
    const int row0 = blockIdx.y * 128, col0 = blockIdx.x * 128;

    const int sm = tid >> 1;
    const int kh = tid & 1;
    size_t arow = row0 + sm; if (arow >= (size_t)M) arow = M - 1;
    const int aswz = (sm >> 1) & 3;

    f32x4 acc[4][4];
    #pragma unroll
    for (int i = 0; i < 4; ++i)
        #pragma unroll
        for (int j = 0; j < 4; ++j)
            acc[i][j] = (f32x4){0.f, 0.f, 0.f, 0.f};

    const int nsteps = Kpad / 32;
    for (int s = 0; s < nsteps; ++s) {
        const int k0 = s * 32;

        // ---------- stage B: async global->LDS, pre-swizzled source ----------
        #pragma unroll
        for (int jj = 0; jj < 2; ++jj) {
            int j = wid * 2 + jj;
            int nl = j * 16 + (lane >> 2);
            int t = lane & 3;
            int ch = t ^ ((nl >> 1) & 3);
            size_t brow = col0 + nl; if (brow >= (size_t)N) brow = N - 1;
            const half_t* gh = Bh + brow * Kpad + k0 + ch * 8;
            const half_t* gl = Bl + brow * Kpad + k0 + ch * 8;
            __builtin_amdgcn_global_load_lds(
                (const __attribute__((address_space(1))) void*)gh,
                (__attribute__((address_space(3))) void*)&sBh[j * 512], 16, 0, 0);
            __builtin_amdgcn_global_load_lds(
                (const __attribute__((address_space(1))) void*)gl,
                (__attribute__((address_space(3))) void*)&sBl[j * 512], 16, 0, 0);
        }

        // ---------- stage A ----------
        if (MODE == 0) {
            const float* A = (const float*)Ain;
            const float* ap = A + arow * K;
            float va[16];
            #pragma unroll
            for (int q = 0; q < 4; ++q) {
                int gk = k0 + kh * 16 + q * 4;
                float4 v = make_float4(0.f, 0.f, 0.f, 0.f);
                if (gk < K) v = *(const float4*)(ap + gk);
                va[q * 4 + 0] = v.x; va[q * 4 + 1] = v.y;
                va[q * 4 + 2] = v.z; va[q * 4 + 3] = v.w;
            }
            #pragma unroll
            for (int c = 0; c < 2; ++c) {
                f16x8 hi, lo;
                #pragma unroll
                for (int j = 0; j < 8; ++j) {
                    float xv = va[c * 8 + j];
                    half_t h = (half_t)xv;
                    hi[j] = h;
                    lo[j] = (half_t)(xv - (float)h);
                }
                int slot = (kh * 2 + c) ^ aswz;
                *(f16x8*)&sAh[sm * 32 + slot * 8] = hi;
                *(f16x8*)&sAl[sm * 32 + slot * 8] = lo;
            }
        } else {
            const unsigned* A = (const unsigned*)Ain;
            #pragma unroll
            for (int c = 0; c < 2; ++c) {
                int u = kh * 2 + c;
                int gk = k0 + u * 8;
                f16x8 hi, lo;
                if (gk < K) {
                    const unsigned* p = A + arow * K + gk;
                    uint4 w0 = *(const uint4*)p;
                    uint4 w1 = *(const uint4*)(p + 4);
                    unsigned wv[8] = {w0.x, w0.y, w0.z, w0.w, w1.x, w1.y, w1.z, w1.w};
                    #pragma unroll
                    for (int j = 0; j < 8; ++j) {
                        union { unsigned short u16; half_t h; } a, b;
                        a.u16 = (unsigned short)(wv[j] & 0xffffu);
                        b.u16 = (unsigned short)(wv[j] >> 16);
                        hi[j] = a.h; lo[j] = b.h;
                    }
                } else {
                    #pragma unroll
                    for (int j = 0; j < 8; ++j) { hi[j] = (half_t)0.f; lo[j] = (half_t)0.f; }
                }
                int slot = u ^ aswz;
                *(f16x8*)&sAh[sm * 32 + slot * 8] = hi;
                *(f16x8*)&sAl[sm * 32 + slot * 8] = lo;
            }
        }
        __syncthreads();

        // ---------- compute: 48 MFMAs per wave, one acc per fragment ----------
        const int frswz = (lr >> 1) & 3;
        f16x8 bhf[4], blf[4];
        #pragma unroll
        for (int fn = 0; fn < 4; ++fn) {
            int noff = (wc * 64 + fn * 16 + lr) * 32 + (ls ^ frswz) * 8;
            bhf[fn] = *(const f16x8*)&sBh[noff];
            blf[fn] = *(const f16x8*)&sBl[noff];
        }
        #pragma unroll
        for (int fm = 0; fm < 4; ++fm) {
            int moff = (wr * 64 + fm * 16 + lr) * 32 + (ls ^ frswz) * 8;
            f16x8 ah = *(const f16x8*)&sAh[moff];
            f16x8 al = *(const f16x8*)&sAl[moff];
            #pragma unroll
            for (int fn = 0; fn < 4; ++fn) {
                acc[fm][fn] = __builtin_amdgcn_mfma_f32_16x16x32_f16(ah, bhf[fn], acc[fm][fn], 0, 0, 0);
                acc[fm][fn] = __builtin_amdgcn_mfma_f32_16x16x32_f16(ah, blf[fn], acc[fm][fn], 0, 0, 0);
                acc[fm][fn] = __builtin_amdgcn_mfma_f32_16x16x32_f16(al, bhf[fn], acc[fm][fn], 0, 0, 0);
            }
        }
        __syncthreads();
    }

    // ---------- epilogue ----------
    if (MODE == 0) {
        #pragma unroll
        for (int fn = 0; fn < 4; ++fn) {
            int gcol = col0 + wc * 64 + fn * 16 + lr;
            if (gcol >= N) continue;
            float bv = bias[gcol];
            #pragma unroll
            for (int fm = 0; fm < 4; ++fm) {
                int growb = row0 + wr * 64 + fm * 16 + ls * 4;
                #pragma unroll
                for (int r = 0; r < 4; ++r) {
                    int grow = growb + r;
                    if (grow >= M) continue;
                    float val = fmaxf(acc[fm][fn][r] + bv, 0.f);
                    half_t h = (half_t)val;
                    half_t l2 = (half_t)(val - (float)h);
                    union { half_t h; unsigned short u; } uh, ul;
                    uh.h = h; ul.h = l2;
                    ((unsigned*)Cout)[(size_t)grow * N + gcol] =
                        ((unsigned)ul.u << 16) | (unsigned)uh.u;
                }
            }
        }
    } else {
        // fused BN column stats: all 64 lanes stay active through the shuffles
        #pragma unroll
        for (int fn = 0; fn < 4; ++fn) {
            int gcol = col0 + wc * 64 + fn * 16 + lr;
            bool colok = (gcol < N);
            float bv = colok ? bias[gcol] : 0.f;
            float s = 0.f, q = 0.f;
            #pragma unroll
            for (int fm = 0; fm < 4; ++fm) {
                int growb = row0 + wr * 64 + fm * 16 + ls * 4;
                #pragma unroll
                for (int r = 0; r < 4; ++r) {
                    int grow = growb + r;
                    float val = acc[fm][fn][r] + bv;
                    if (colok && grow < M) {
                        ((float*)Cout)[(size_t)grow * N + gcol] = val;
                        s += val;
                        q = fmaf(val, val, q);
                    }
                }
            }
            // reduce across ls (lanes ^16, ^32 share the same column lr)
            s += __shfl_xor(s, 16); q += __shfl_xor(q, 16);
            s += __shfl_xor(s, 32); q += __shfl_xor(q, 32);
            if (ls == 0 && colok) {
                atomicAdd(&stats[gcol], s);
                atomicAdd(&stats[EMB + gcol], q);
            }
        }
    }
}

// ---------------------------------------------------------------------------
__global__ void k_bn_finalize(float* __restrict__ stats, const float* __restrict__ gamma,
                              const float* __restrict__ beta, int N) {
    int c = threadIdx.x;
    if (c >= EMB) return;
    float inv_n = 1.f / (float)N;
    float mu = stats[c] * inv_n;
    float var = stats[EMB + c] * inv_n - mu * mu;
    float sc = gamma[c] * rsqrtf(var + EPS);
    stats[2 * EMB + c] = sc;
    stats[3 * EMB + c] = beta[c] - mu * sc;
}

__global__ void k_bn_apply(const float* __restrict__ h2, const float* __restrict__ stats,
                           float* __restrict__ h, int N, int relu) {
    const float4* x4 = (const float4*)h2;
    float4* o4 = (float4*)h;
    const float4* sc4 = (const float4*)(stats + 2 * EMB);
    const float4* sh4 = (const float4*)(stats + 3 * EMB);
    int total = N * EMB4;
    for (int i = blockIdx.x * blockDim.x + threadIdx.x; i < total;
         i += gridDim.x * blockDim.x) {
        int c = i % EMB4;
        float4 v = x4[i], s = sc4[c], t = sh4[c];
        float4 r;
        r.x = fmaf(v.x, s.x, t.x);
        r.y = fmaf(v.y, s.y, t.y);
        r.z = fmaf(v.z, s.z, t.z);
        r.w = fmaf(v.w, s.w, t.w);
        if (relu) {
            r.x = fmaxf(r.x, 0.f); r.y = fmaxf(r.y, 0.f);
            r.z = fmaxf(r.z, 0.f); r.w = fmaxf(r.w, 0.f);
        }
        o4[i] = r;
    }
}

// ---------------------------------------------------------------------------
extern "C" void kernel_launch(void* const* d_in, const int* in_sizes, int n_in,
                              void* d_out, int out_size, void* d_ws, size_t ws_size,
                              hipStream_t stream) {
    const int*   x      = (const int*)d_in[0];
    const int*   ei     = (const int*)d_in[1];
    const int*   ea     = (const int*)d_in[2];
    const float* x_emb1 = (const float*)d_in[3];
    const float* x_emb2 = (const float*)d_in[4];
    const float* e1     = (const float*)d_in[5];
    const float* e2     = (const float*)d_in[6];
    const float* W1     = (const float*)d_in[7];
    const float* b1     = (const float*)d_in[8];
    const float* W2     = (const float*)d_in[9];
    const float* b2     = (const float*)d_in[10];
    const float* gamma  = (const float*)d_in[11];
    const float* beta   = (const float*)d_in[12];
    float* out = (float*)d_out;

    int N = in_sizes[0] / 2;
    int E = in_sizes[2] / 2;
    int L = in_sizes[7] / (EMB * 2 * EMB);

    // ws layout (floats): stats @0 (1216) | start @1216 (50001 ints) |
    // packed @51220 (E ints) | agg @ aligned (N*EMB) | hm (N*600 u32)
    // deg/cursor alias the agg region (dead until first k_agg_csr).
    float* ws    = (float*)d_ws;
    float* stats = ws;
    int*   startA = (int*)(ws + 1216);
    int*   packed = (int*)(ws + 1216 + 50004);
    size_t agg_ofs = 1216 + 50004 + (size_t)E;
    agg_ofs = (agg_ofs + 7) & ~(size_t)7;          // 32B align
    float* agg = ws + agg_ofs;
    unsigned* hm = (unsigned*)(agg + (size_t)N * EMB);
    int* deg    = (int*)agg;
    int* cursor = deg + 50004;

    // weight planes live in d_out's dead window (between agg and bn_apply)
    half_t* b1h = (half_t*)d_out;
    half_t* b1l = b1h + (size_t)600 * 320;
    half_t* b2h = (half_t*)d_out;
    half_t* b2l = b2h + (size_t)300 * 608;

    // ---- one-time: CSR build + h init ----
    k_zero<<<(N + 256) / 256, 256, 0, stream>>>(deg, N + 1);
    k_hist<<<1024, 256, 0, stream>>>(ei, deg, E);
    k_prefix<<<1, 1024, 0, stream>>>(deg, startA, cursor, N);
    k_permute<<<1024, 256, 0, stream>>>(ei, ea, cursor, packed, E);
    k_hinit<<<2048, 256, 0, stream>>>(x, x_emb1, x_emb2, out, N);

    int rowblks = (N + 127) / 128;
    for (int l = 0; l < L; ++l) {
        const float* e1l = e1 + (size_t)l * 6 * EMB;
        const float* e2l = e2 + (size_t)l * 3 * EMB;

        k_agg_csr<<<(N + 3) / 4, 256, 0, stream>>>(startA, packed, out, e1l, e2l,
                                                   agg, stats, N);

        // h (d_out) is dead from here until bn_apply -> borrow for weight planes
        k_cvtB<<<128, 256, 0, stream>>>(W1 + (size_t)l * EMB * 2 * EMB,
                                        b1h, b1l, EMB, 2 * EMB, 320);
        dim3 g1(5, rowblks);
        k_mfma_gemm<0><<<g1, 256, 0, stream>>>(
            agg, b1h, b1l, b1 + (size_t)l * 2 * EMB, hm, nullptr,
            N, 2 * EMB, EMB, 320);

        k_cvtB<<<128, 256, 0, stream>>>(W2 + (size_t)l * 2 * EMB * EMB,
                                        b2h, b2l, 2 * EMB, EMB, 608);
        dim3 g2(3, rowblks);
        k_mfma_gemm<1><<<g2, 256, 0, stream>>>(
            hm, b2h, b2l, b2 + (size_t)l * EMB, agg, stats,
            N, EMB, 2 * EMB, 608);

        k_bn_finalize<<<1, 320, 0, stream>>>(stats, gamma + (size_t)l * EMB,
                                             beta + (size_t)l * EMB, N);
        k_bn_apply<<<2048, 256, 0, stream>>>(agg, stats, out, N, (l < L - 1) ? 1 : 0);
    }
}